// Round 16
// baseline (169.703 us; speedup 1.0000x reference)
//
#include <hip/hip_runtime.h>
#include <math.h>

#define DM 256
#define NROWS 8192
#define NCOLS 8192
#define JSPLIT 4
#define LOG2E 1.44269504f
#define LN2F 0.6931471805599453f

typedef __attribute__((ext_vector_type(8)))  __bf16 bf16x8;
typedef __attribute__((ext_vector_type(4)))  __bf16 bf16x4;
typedef __attribute__((ext_vector_type(16))) float  f32x16;

#if __has_builtin(__builtin_amdgcn_exp2f)
#define EXP2F(x) __builtin_amdgcn_exp2f(x)
#else
#define EXP2F(x) exp2f(x)
#endif

__device__ __forceinline__ f32x16 fzero16() {
  f32x16 z;
#pragma unroll
  for (int i = 0; i < 16; ++i) z[i] = 0.f;
  return z;
}

__device__ __forceinline__ void load_lds16(const void* g, void* l) {
  __builtin_amdgcn_global_load_lds(
      (const __attribute__((address_space(1))) unsigned int*)g,
      (__attribute__((address_space(3))) unsigned int*)l, 16, 0, 0);
}

__device__ __forceinline__ bf16x8 cvt8(float4 a, float4 b) {
  bf16x8 v;
  v[0] = (__bf16)a.x; v[1] = (__bf16)a.y; v[2] = (__bf16)a.z; v[3] = (__bf16)a.w;
  v[4] = (__bf16)b.x; v[5] = (__bf16)b.y; v[6] = (__bf16)b.z; v[7] = (__bf16)b.w;
  return v;
}

__device__ __forceinline__ unsigned cvtpk_bf16(float lo, float hi) {
  unsigned r;
  asm("v_cvt_pk_bf16_f32 %0, %1, %2" : "=v"(r) : "v"(lo), "v"(hi));
  return r;
}
__device__ __forceinline__ void swap32(unsigned& a, unsigned& b) {
  asm("v_permlane32_swap_b32 %0, %1" : "+v"(a), "+v"(b));
}

// ---- prep: W transpose+cvt (blocks 0..63) + label hist + loss zero (64) ----
__global__ __launch_bounds__(256) void prep_kernel(
    const float* __restrict__ W0, const float* __restrict__ W1,
    const float* __restrict__ W2, const float* __restrict__ W3,
    __bf16* __restrict__ wt, const int* __restrict__ lab2,
    int* __restrict__ counts, float* __restrict__ loss_out) {
  const int t = threadIdx.x;
  if (blockIdx.x == 64) {
    __shared__ int h[16];
    if (t < 16) h[t] = 0;
    __syncthreads();
#pragma unroll
    for (int i = 0; i < 8; ++i) {
      int4 a = *(const int4*)&lab2[t * 32 + i * 4];
      atomicAdd(&h[a.x & 15], 1); atomicAdd(&h[a.y & 15], 1);
      atomicAdd(&h[a.z & 15], 1); atomicAdd(&h[a.w & 15], 1);
    }
    __syncthreads();
    if (t < 16) counts[t] = h[t];
    if (t == 0) *loss_out = 0.f;
    return;
  }
  __shared__ float Ls[64][65];
  const int mat = blockIdx.x >> 4;
  const int k0 = ((blockIdx.x >> 2) & 3) * 64;
  const int n0 = (blockIdx.x & 3) * 64;
  const float* W = mat == 0 ? W0 : mat == 1 ? W1 : mat == 2 ? W2 : W3;
#pragma unroll
  for (int i = 0; i < 4; ++i) {
    int idx = t + i * 256;
    int row = idx >> 4, c4 = (idx & 15) * 4;
    float4 v = *(const float4*)&W[(size_t)(k0 + row) * DM + n0 + c4];
    Ls[row][c4] = v.x; Ls[row][c4 + 1] = v.y;
    Ls[row][c4 + 2] = v.z; Ls[row][c4 + 3] = v.w;
  }
  __syncthreads();
#pragma unroll
  for (int i = 0; i < 2; ++i) {
    int c = t + i * 256;
    int n = c >> 3, kc = (c & 7) * 8;
    bf16x8 v;
#pragma unroll
    for (int j = 0; j < 8; ++j) v[j] = (__bf16)Ls[kc + j][n];
    *(bf16x8*)&wt[(size_t)mat * 65536 + (size_t)(n0 + n) * DM + k0 + kc] = v;
  }
}

// ---- fused 3-projection MFMA GEMM (grid (64,1,3); internal n-tile loop) ----
__global__ __launch_bounds__(256) void proj3_kernel(
    const float* __restrict__ x1, const float* __restrict__ x2,
    const __bf16* __restrict__ wt, const float* __restrict__ bxq,
    const float* __restrict__ bxk, const float* __restrict__ bxv,
    __bf16* __restrict__ xqb, __bf16* __restrict__ xkb,
    __bf16* __restrict__ xvT) {
  __shared__ __bf16 W_s[64 * 256];
  const int t = threadIdx.x;
  const int w = t >> 6, l = t & 63, g = l >> 5, l31 = l & 31;
  const int mb = blockIdx.x, mat = blockIdx.z;
  const float* A = (mat == 0) ? x1 : x2;
  const __bf16* wmat = wt + (size_t)mat * 65536;
  const float* bias = (mat == 0) ? bxq : (mat == 1) ? bxk : bxv;
  const float oscale = (mat == 0) ? (0.0625f * LOG2E) : 1.0f;
  const int arow = mb * 128 + w * 32 + l31;
  bf16x8 af[16];
#pragma unroll
  for (int ks = 0; ks < 16; ++ks) {
    float4 u0 = *(const float4*)&A[(size_t)arow * DM + ks * 16 + g * 8];
    float4 u1 = *(const float4*)&A[(size_t)arow * DM + ks * 16 + g * 8 + 4];
    af[ks] = cvt8(u0, u1);
  }
  const int mrowbase = mb * 128 + w * 32;
#pragma unroll 1
  for (int nt = 0; nt < 4; ++nt) {
    const int n0 = nt * 64;
#pragma unroll
    for (int o = 0; o < 8; ++o) {
      int cbase = w * 64 + o * 256;
      int chunk = cbase + l;
      int n = chunk >> 5, kb = (chunk & 31) * 16;
      load_lds16((const char*)wmat + (size_t)(n0 + n) * 512 + (kb ^ ((n & 7) << 4)),
                 (char*)W_s + (size_t)cbase * 16);
    }
    __syncthreads();  // staging landed (implicit vmcnt drain)
    f32x16 acc2[2];
    acc2[0] = fzero16(); acc2[1] = fzero16();
#pragma unroll
    for (int ks = 0; ks < 16; ++ks)
#pragma unroll
      for (int tt = 0; tt < 2; ++tt) {
        int n = tt * 32 + l31;
        bf16x8 b = *(const bf16x8*)&W_s[n * DM + ((ks * 16 + g * 8) ^ ((n & 7) << 3))];
        acc2[tt] = __builtin_amdgcn_mfma_f32_32x32x16_bf16(af[ks], b, acc2[tt], 0, 0, 0);
      }
#pragma unroll
    for (int tt = 0; tt < 2; ++tt) {
      const int col = n0 + tt * 32 + l31;
      const float bv = bias[col];
      if (mat == 2) {
#pragma unroll
        for (int rq = 0; rq < 4; ++rq) {
          int m = mrowbase + 8 * rq + 4 * g;
          bf16x4 v;
#pragma unroll
          for (int j = 0; j < 4; ++j) v[j] = (__bf16)(acc2[tt][rq * 4 + j] + bv);
          *(bf16x4*)&xvT[(size_t)col * NROWS + m] = v;
        }
      } else {
        __bf16* dst = (mat == 0) ? xqb : xkb;
#pragma unroll
        for (int rq = 0; rq < 4; ++rq)
#pragma unroll
          for (int j = 0; j < 4; ++j) {
            int m = mrowbase + j + 8 * rq + 4 * g;
            dst[(size_t)m * DM + col] = (__bf16)((acc2[tt][rq * 4 + j] + bv) * oscale);
          }
      }
    }
    __syncthreads();  // all waves done reading W_s before next stage
  }
}

// ---- flash staging (JB=32): K tile [32][256] + VT tile [256][32] ----
// K swizzle EXTENDED to 16-row involution (granule ^ (j&15)) -> within a
// wave quarter all 16 lanes hit distinct granule positions (2-way max
// aliasing = free, m136). Same involution on read side below.
__device__ __forceinline__ void stage_tiles32(
    const __bf16* __restrict__ xkb, const __bf16* __restrict__ xvT,
    __bf16* Kbuf, __bf16* Vbuf, int j0, int w, int l) {
#pragma unroll
  for (int o = 0; o < 4; ++o) {
    int cbase = o * 256 + w * 64;
    int c = cbase + l;
    int j = c >> 5, kg = (c & 31) * 16;
    load_lds16((const char*)xkb + (size_t)(j0 + j) * 512 + (kg ^ ((j & 15) << 4)),
               (char*)Kbuf + (size_t)cbase * 16);
  }
#pragma unroll
  for (int o = 0; o < 4; ++o) {
    int cbase = o * 256 + w * 64;
    int c = cbase + l;
    int p = c ^ ((c >> 3) & 7);  // involution (bits>=3 unmodified)
    int v = p >> 2, jg = p & 3;
    load_lds16((const char*)xvT + (size_t)v * 16384 + (size_t)j0 * 2 + jg * 16,
               (char*)Vbuf + (size_t)cbase * 16);
  }
}

// ---- fused label-masked softmax-contrastive flash kernel ----
// r15 structure (JB=32, 2 blocks/CU, 4 waves = 2qh x 2vh, acc[4], single
// barrier/iter, depth-1 prefetch) with the K-read XOR extended to l31&15.
__global__ __launch_bounds__(256, 2) void flash_kernel(
    const __bf16* __restrict__ xqb, const __bf16* __restrict__ xkb,
    const __bf16* __restrict__ xvT, const int* __restrict__ lab1,
    const int* __restrict__ lab2, __bf16* __restrict__ accp,
    float* __restrict__ sgp, float* __restrict__ psp) {
  __shared__ __align__(16) char smem[67584];
  __bf16* K_s0 = (__bf16*)smem;                // [2][32*256] = 32 KB
  __bf16* VT_s0 = (__bf16*)(smem + 32768);     // [2][256*32] = 32 KB
  unsigned* lpk = (unsigned*)(smem + 65536);   // 2 KB packed u8 labels (2048 j)

  const int t = threadIdx.x;
  const int w = t >> 6, l = t & 63, g = l >> 5, l31 = l & 31;
  const int qh = w >> 1, vh = w & 1;
  const int f = blockIdx.x;
  const int js = f & 3;   // one chunk per XCD under round-robin
  const int qb = f >> 2;  // 0..127
  const int j0base = js * 2048;

  {  // pack this chunk's labels as bytes (256 thr x 8 labels)
#pragma unroll
    for (int i = 0; i < 2; ++i) {
      int idx = t * 2 + i;
      int4 lv = *(const int4*)&lab2[j0base + idx * 4];
      lpk[idx] = (unsigned)(lv.x & 255) | ((unsigned)(lv.y & 255) << 8) |
                 ((unsigned)(lv.z & 255) << 16) | ((unsigned)(lv.w & 255) << 24);
    }
  }

  const int qrow = qb * 64 + qh * 32 + l31;
  bf16x8 qf[16];
#pragma unroll
  for (int ks = 0; ks < 16; ++ks)
    qf[ks] = *(const bf16x8*)&xqb[(size_t)qrow * DM + ks * 16 + g * 8];
  const unsigned lax = (unsigned)(lab1[qrow] & 255) * 0x01010101u;

  float s_p = 0.f, ps_p = 0.f;
  f32x16 acc[4];
#pragma unroll
  for (int tt = 0; tt < 4; ++tt) acc[tt] = fzero16();

  __syncthreads();  // lpk visible; all prologue vmem drained (vmcnt==0)

  stage_tiles32(xkb, xvT, K_s0, VT_s0, j0base, w, l);  // tile 0 only

  union PaU { unsigned uu[4]; bf16x8 v; };

#pragma unroll 1
  for (int it = 0; it < 64; ++it) {
    // stage(it) is the only outstanding load batch -> vmcnt(0) == landed
    asm volatile("s_waitcnt vmcnt(0)" ::: "memory");
    __builtin_amdgcn_sched_barrier(0);
    __builtin_amdgcn_s_barrier();  // all waves done with iter it-1
    __builtin_amdgcn_sched_barrier(0);

    // prefetch tile it+1 into buf((it+1)&1): last read at iter it-1 -> free
    if (it + 1 < 64)
      stage_tiles32(xkb, xvT, K_s0 + ((it + 1) & 1) * 8192,
                    VT_s0 + ((it + 1) & 1) * 8192, j0base + (it + 1) * 32, w, l);

    const __bf16* Kc = K_s0 + (it & 1) * 8192;
    const __bf16* Vc = VT_s0 + (it & 1) * 8192;

    // ---- S = K@Q^T (32 j): c[j on regs][q on lanes] ----
    f32x16 c = fzero16();
    __builtin_amdgcn_s_setprio(1);
#pragma unroll
    for (int ks = 0; ks < 16; ++ks) {
      bf16x8 kb = *(const bf16x8*)&Kc[l31 * DM +
                                      ((ks * 16 + g * 8) ^ ((l31 & 15) << 3))];
      c = __builtin_amdgcn_mfma_f32_32x32x16_bf16(kb, qf[ks], c, 0, 0, 0);
    }
    __builtin_amdgcn_s_setprio(0);

    // ---- softmax + mask (c = 1.4427*S; exp2); stats for own j-half ----
    unsigned lb[4];
#pragma unroll
    for (int q4 = 0; q4 < 4; ++q4)
      lb[q4] = lpk[it * 8 + q4 * 2 + g] ^ lax;
#pragma unroll
    for (int r = 0; r < 16; ++r) {
      float sv = c[r];
      float p = EXP2F(sv);
      bool mt = ((lb[r >> 2] >> ((r & 3) * 8)) & 255u) == 0u;
      if ((r >> 3) == vh) {  // compile-time predicate per unrolled r
        s_p += p;
        ps_p += mt ? sv : 0.f;
      }
      c[r] = mt ? p : 0.f;
    }
    unsigned u[8];
#pragma unroll
    for (int i = 0; i < 8; ++i) u[i] = cvtpk_bf16(c[2 * i], c[2 * i + 1]);
    swap32(u[0], u[2]); swap32(u[1], u[3]);
    swap32(u[4], u[6]); swap32(u[5], u[7]);
    PaU p0, p1;
    p0.uu[0] = u[0]; p0.uu[1] = u[1]; p0.uu[2] = u[2]; p0.uu[3] = u[3];
    p1.uu[0] = u[4]; p1.uu[1] = u[5]; p1.uu[2] = u[6]; p1.uu[3] = u[7];

    // ---- PV: acc[32q on regs][128v on lanes] += P @ V (32 j) ----
    __builtin_amdgcn_s_setprio(1);
#pragma unroll
    for (int tt = 0; tt < 4; ++tt) {
      int v = vh * 128 + tt * 32 + l31;
#pragma unroll
      for (int kj = 0; kj < 2; ++kj) {
        int pg = v * 4 + kj * 2 + g;            // logical 16B granule
        int lg = pg ^ ((pg >> 3) & 7);          // swizzled LDS granule
        bf16x8 vb = *(const bf16x8*)&Vc[lg * 8];
        acc[tt] = __builtin_amdgcn_mfma_f32_32x32x16_bf16(
            kj ? p1.v : p0.v, vb, acc[tt], 0, 0, 0);
      }
    }
    __builtin_amdgcn_s_setprio(0);
    // (no second barrier: buffer overwrite is protected by the NEXT iter's
    // top barrier; ds-read results are consumed before that barrier.)
  }

  // ---- epilogue: pair-combine stats (lpk space dead) + accp stores ----
  s_p += __shfl_xor(s_p, 32);
  ps_p += __shfl_xor(ps_p, 32);
  float* sred = (float*)(smem + 65536);  // 4 waves x 32 x 2 f32 = 1 KB
  if (l < 32) {
    sred[(w * 32 + l31) * 2] = s_p;
    sred[(w * 32 + l31) * 2 + 1] = ps_p;
  }
  __syncthreads();
  if (vh == 0 && l < 32) {
    float stot = s_p + sred[(((w ^ 1) * 32) + l31) * 2];
    float ptot = ps_p + sred[(((w ^ 1) * 32) + l31) * 2 + 1];
    sgp[(size_t)js * NROWS + qrow] = stot;
    psp[(size_t)js * NROWS + qrow] = ptot;
  }
  // stage acc (bf16) into padded LDS tile [64][264]
  __bf16* st = (__bf16*)smem;
#pragma unroll
  for (int tt = 0; tt < 4; ++tt)
#pragma unroll
    for (int r = 0; r < 16; ++r) {
      int row = qh * 32 + (r & 3) + 8 * (r >> 2) + 4 * g;
      int col = vh * 128 + tt * 32 + l31;
      st[row * 264 + col] = (__bf16)acc[tt][r];
    }
  __syncthreads();
  // linear copy LDS -> accp: 16B/lane, consecutive lanes -> consecutive 16B
  __bf16* dst = accp + ((size_t)js * NROWS + qb * 64) * DM;
#pragma unroll
  for (int p = 0; p < 8; ++p) {
    int off16 = p * 256 + t;   // 16B-granule index, 0..2047 (32 KB payload)
    int row = off16 >> 5;      // 32 granules (512 B) per row
    int colg = off16 & 31;
    bf16x8 v = *(const bf16x8*)&st[row * 264 + colg * 8];
    *(bf16x8*)&dst[(size_t)row * DM + colg * 8] = v;
  }
}

// ---- combine: sum 4 js partials; out=acc/s; res=x1+out; normalize; loss ----
__global__ __launch_bounds__(1024) void combine_kernel(
    const __bf16* __restrict__ accp, const float* __restrict__ sgp,
    const float* __restrict__ psp, const int* __restrict__ counts,
    const int* __restrict__ lab1, const float* __restrict__ x1,
    __bf16* __restrict__ resn, float* __restrict__ loss_out) {
  __shared__ float lred[16];
  const int t = threadIdx.x;
  const int rr = t >> 6;
  const int r = blockIdx.x * 16 + rr;
  const int l = t & 63;
  float s = 0.f;
#pragma unroll
  for (int js = 0; js < JSPLIT; ++js) s += sgp[(size_t)js * NROWS + r];
  const float inv = 1.f / s;
  float a0 = 0.f, a1 = 0.f, a2 = 0.f, a3 = 0.f;
#pragma unroll
  for (int js = 0; js < JSPLIT; ++js) {
    bf16x4 v = *(const bf16x4*)&accp[((size_t)js * NROWS + r) * DM + l * 4];
    a0 += (float)v[0]; a1 += (float)v[1]; a2 += (float)v[2]; a3 += (float)v[3];
  }
  float4 x = *(const float4*)&x1[(size_t)r * DM + l * 4];
  float o0 = x.x + a0 * inv, o1 = x.y + a1 * inv;
  float o2 = x.z + a2 * inv, o3 = x.w + a3 * inv;
  float sq = o0 * o0 + o1 * o1 + o2 * o2 + o3 * o3;
#pragma unroll
  for (int m = 1; m < 64; m <<= 1) sq += __shfl_xor(sq, m);
  const float nrm = 1.f / fmaxf(sqrtf(sq), 1e-12f);
  bf16x4 o;
  o[0] = (__bf16)(o0 * nrm); o[1] = (__bf16)(o1 * nrm);
  o[2] = (__bf16)(o2 * nrm); o[3] = (__bf16)(o3 * nrm);
  *(bf16x4*)&resn[(size_t)r * DM + l * 4] = o;
  if (l == 0) {
    float ps = 0.f;
#pragma unroll
    for (int js = 0; js < JSPLIT; ++js) ps += psp[(size_t)js * NROWS + r];
    float np = (float)counts[lab1[r] & 15];
    lred[rr] = (ps * LN2F - np * logf(s)) / fmaxf(np, 1.f);
  }
  __syncthreads();
  if (t == 0) {
    float accl = 0.f;
#pragma unroll
    for (int i = 0; i < 16; ++i) accl += lred[i];
    atomicAdd(loss_out, -accl * (1.f / 8192.f));
  }
}

// ---- final GEMM (grid (64); internal nt loop, A-frags loaded once):
// out[m][n] = relu(resn@Wout + bout), scalar f32 stores (out+1 misaligned) ----
__global__ __launch_bounds__(256) void final_gemm(
    const __bf16* __restrict__ A, const __bf16* __restrict__ wmat,
    const float* __restrict__ bias, float* __restrict__ C) {
  __shared__ __bf16 W_s[64 * 256];
  const int t = threadIdx.x;
  const int w = t >> 6, l = t & 63, g = l >> 5, l31 = l & 31;
  const int mb = blockIdx.x;
  const int arow = mb * 128 + w * 32 + l31;
  bf16x8 af[16];
#pragma unroll
  for (int ks = 0; ks < 16; ++ks)
    af[ks] = *(const bf16x8*)&A[(size_t)arow * DM + ks * 16 + g * 8];
  const int mrowbase = mb * 128 + w * 32;
#pragma unroll 1
  for (int nt = 0; nt < 4; ++nt) {
    const int n0 = nt * 64;
#pragma unroll
    for (int o = 0; o < 8; ++o) {
      int cbase = w * 64 + o * 256;
      int chunk = cbase + l;
      int n = chunk >> 5, kb = (chunk & 31) * 16;
      load_lds16((const char*)wmat + (size_t)(n0 + n) * 512 + (kb ^ ((n & 7) << 4)),
                 (char*)W_s + (size_t)cbase * 16);
    }
    __syncthreads();  // staging landed
    f32x16 acc2[2];
    acc2[0] = fzero16(); acc2[1] = fzero16();
#pragma unroll
    for (int ks = 0; ks < 16; ++ks)
#pragma unroll
      for (int tt = 0; tt < 2; ++tt) {
        int n = tt * 32 + l31;
        bf16x8 b = *(const bf16x8*)&W_s[n * DM + ((ks * 16 + g * 8) ^ ((n & 7) << 3))];
        acc2[tt] = __builtin_amdgcn_mfma_f32_32x32x16_bf16(af[ks], b, acc2[tt], 0, 0, 0);
      }
#pragma unroll
    for (int tt = 0; tt < 2; ++tt) {
      const int col = n0 + tt * 32 + l31;
      const float bv = bias[col];
#pragma unroll
      for (int rq = 0; rq < 4; ++rq)
#pragma unroll
        for (int j = 0; j < 4; ++j) {
          int m = mrowbase + j + 8 * rq + 4 * g;
          C[(size_t)m * DM + col] = fmaxf(acc2[tt][rq * 4 + j] + bv, 0.f);
        }
    }
    __syncthreads();  // all waves done reading W_s before next stage
  }
}

extern "C" void kernel_launch(void* const* d_in, const int* in_sizes, int n_in,
                              void* d_out, int out_size, void* d_ws, size_t ws_size,
                              hipStream_t stream) {
  const float* x1 = (const float*)d_in[0];
  const float* x2 = (const float*)d_in[1];
  const int* lab1 = (const int*)d_in[2];
  const int* lab2 = (const int*)d_in[3];
  const float* Wxq = (const float*)d_in[4];
  const float* bxq = (const float*)d_in[5];
  const float* Wxk = (const float*)d_in[6];
  const float* bxk = (const float*)d_in[7];
  const float* Wxv = (const float*)d_in[8];
  const float* bxv = (const float*)d_in[9];
  const float* Wout = (const float*)d_in[10];
  const float* bout = (const float*)d_in[11];
  float* out = (float*)d_out;

  char* ws = (char*)d_ws;
  __bf16* xqb = (__bf16*)ws;                                // 4 MB
  __bf16* xkb = (__bf16*)(ws + (4 << 20));                  // 4 MB
  __bf16* xvT = (__bf16*)(ws + (8 << 20));                  // 4 MB [256][8192]
  __bf16* wt  = (__bf16*)(ws + (12 << 20));                 // 512 KB
  int* counts = (int*)(ws + (12 << 20) + (512 << 10));      // 64 B
  __bf16* accp = (__bf16*)(ws + (13 << 20));                // 16 MB [4][8192][256]
  float* sgp  = (float*)(ws + (29 << 20));                  // 128 KB [4][8192]
  float* psp  = (float*)(ws + (29 << 20) + (128 << 10));    // 128 KB
  __bf16* resn = xqb;  // alias: xqb dead after flash

  prep_kernel<<<dim3(65), dim3(256), 0, stream>>>(Wxq, Wxk, Wxv, Wout, wt,
                                                  lab2, counts, out);

  proj3_kernel<<<dim3(64, 1, 3), dim3(256), 0, stream>>>(
      x1, x2, wt, bxq, bxk, bxv, xqb, xkb, xvT);

  flash_kernel<<<dim3(512), dim3(256), 0, stream>>>(
      xqb, xkb, xvT, lab1, lab2, accp, sgp, psp);

  combine_kernel<<<dim3(512), dim3(1024), 0, stream>>>(
      accp, sgp, psp, counts, lab1, x1, resn, out);

  final_gemm<<<dim3(64), dim3(256), 0, stream>>>(resn, wt + 196608, bout,
                                                 out + 1);
}

// Round 17
// 167.484 us; speedup vs baseline: 1.0132x; 1.0132x over previous
//
#include <hip/hip_runtime.h>
#include <math.h>

#define DM 256
#define NROWS 8192
#define NCOLS 8192
#define JSPLIT 4
#define LOG2E 1.44269504f
#define LN2F 0.6931471805599453f

typedef __attribute__((ext_vector_type(8)))  __bf16 bf16x8;
typedef __attribute__((ext_vector_type(4)))  __bf16 bf16x4;
typedef __attribute__((ext_vector_type(16))) float  f32x16;

#if __has_builtin(__builtin_amdgcn_exp2f)
#define EXP2F(x) __builtin_amdgcn_exp2f(x)
#else
#define EXP2F(x) exp2f(x)
#endif

__device__ __forceinline__ f32x16 fzero16() {
  f32x16 z;
#pragma unroll
  for (int i = 0; i < 16; ++i) z[i] = 0.f;
  return z;
}

__device__ __forceinline__ void load_lds16(const void* g, void* l) {
  __builtin_amdgcn_global_load_lds(
      (const __attribute__((address_space(1))) unsigned int*)g,
      (__attribute__((address_space(3))) unsigned int*)l, 16, 0, 0);
}

__device__ __forceinline__ bf16x8 cvt8(float4 a, float4 b) {
  bf16x8 v;
  v[0] = (__bf16)a.x; v[1] = (__bf16)a.y; v[2] = (__bf16)a.z; v[3] = (__bf16)a.w;
  v[4] = (__bf16)b.x; v[5] = (__bf16)b.y; v[6] = (__bf16)b.z; v[7] = (__bf16)b.w;
  return v;
}

__device__ __forceinline__ unsigned cvtpk_bf16(float lo, float hi) {
  unsigned r;
  asm("v_cvt_pk_bf16_f32 %0, %1, %2" : "=v"(r) : "v"(lo), "v"(hi));
  return r;
}
__device__ __forceinline__ void swap32(unsigned& a, unsigned& b) {
  asm("v_permlane32_swap_b32 %0, %1" : "+v"(a), "+v"(b));
}

// ---- prep: W transpose+cvt (blocks 0..63) + label hist + loss zero (64) ----
__global__ __launch_bounds__(256) void prep_kernel(
    const float* __restrict__ W0, const float* __restrict__ W1,
    const float* __restrict__ W2, const float* __restrict__ W3,
    __bf16* __restrict__ wt, const int* __restrict__ lab2,
    int* __restrict__ counts, float* __restrict__ loss_out) {
  const int t = threadIdx.x;
  if (blockIdx.x == 64) {
    __shared__ int h[16];
    if (t < 16) h[t] = 0;
    __syncthreads();
#pragma unroll
    for (int i = 0; i < 8; ++i) {
      int4 a = *(const int4*)&lab2[t * 32 + i * 4];
      atomicAdd(&h[a.x & 15], 1); atomicAdd(&h[a.y & 15], 1);
      atomicAdd(&h[a.z & 15], 1); atomicAdd(&h[a.w & 15], 1);
    }
    __syncthreads();
    if (t < 16) counts[t] = h[t];
    if (t == 0) *loss_out = 0.f;
    return;
  }
  __shared__ float Ls[64][65];
  const int mat = blockIdx.x >> 4;
  const int k0 = ((blockIdx.x >> 2) & 3) * 64;
  const int n0 = (blockIdx.x & 3) * 64;
  const float* W = mat == 0 ? W0 : mat == 1 ? W1 : mat == 2 ? W2 : W3;
#pragma unroll
  for (int i = 0; i < 4; ++i) {
    int idx = t + i * 256;
    int row = idx >> 4, c4 = (idx & 15) * 4;
    float4 v = *(const float4*)&W[(size_t)(k0 + row) * DM + n0 + c4];
    Ls[row][c4] = v.x; Ls[row][c4 + 1] = v.y;
    Ls[row][c4 + 2] = v.z; Ls[row][c4 + 3] = v.w;
  }
  __syncthreads();
#pragma unroll
  for (int i = 0; i < 2; ++i) {
    int c = t + i * 256;
    int n = c >> 3, kc = (c & 7) * 8;
    bf16x8 v;
#pragma unroll
    for (int j = 0; j < 8; ++j) v[j] = (__bf16)Ls[kc + j][n];
    *(bf16x8*)&wt[(size_t)mat * 65536 + (size_t)(n0 + n) * DM + k0 + kc] = v;
  }
}

// ---- fused 3-projection MFMA GEMM (grid (64,1,3); internal n-tile loop) ----
__global__ __launch_bounds__(256) void proj3_kernel(
    const float* __restrict__ x1, const float* __restrict__ x2,
    const __bf16* __restrict__ wt, const float* __restrict__ bxq,
    const float* __restrict__ bxk, const float* __restrict__ bxv,
    __bf16* __restrict__ xqb, __bf16* __restrict__ xkb,
    __bf16* __restrict__ xvT) {
  __shared__ __bf16 W_s[64 * 256];
  const int t = threadIdx.x;
  const int w = t >> 6, l = t & 63, g = l >> 5, l31 = l & 31;
  const int mb = blockIdx.x, mat = blockIdx.z;
  const float* A = (mat == 0) ? x1 : x2;
  const __bf16* wmat = wt + (size_t)mat * 65536;
  const float* bias = (mat == 0) ? bxq : (mat == 1) ? bxk : bxv;
  const float oscale = (mat == 0) ? (0.0625f * LOG2E) : 1.0f;
  const int arow = mb * 128 + w * 32 + l31;
  bf16x8 af[16];
#pragma unroll
  for (int ks = 0; ks < 16; ++ks) {
    float4 u0 = *(const float4*)&A[(size_t)arow * DM + ks * 16 + g * 8];
    float4 u1 = *(const float4*)&A[(size_t)arow * DM + ks * 16 + g * 8 + 4];
    af[ks] = cvt8(u0, u1);
  }
  const int mrowbase = mb * 128 + w * 32;
#pragma unroll 1
  for (int nt = 0; nt < 4; ++nt) {
    const int n0 = nt * 64;
#pragma unroll
    for (int o = 0; o < 8; ++o) {
      int cbase = w * 64 + o * 256;
      int chunk = cbase + l;
      int n = chunk >> 5, kb = (chunk & 31) * 16;
      load_lds16((const char*)wmat + (size_t)(n0 + n) * 512 + (kb ^ ((n & 7) << 4)),
                 (char*)W_s + (size_t)cbase * 16);
    }
    __syncthreads();  // staging landed (implicit vmcnt drain)
    f32x16 acc2[2];
    acc2[0] = fzero16(); acc2[1] = fzero16();
#pragma unroll
    for (int ks = 0; ks < 16; ++ks)
#pragma unroll
      for (int tt = 0; tt < 2; ++tt) {
        int n = tt * 32 + l31;
        bf16x8 b = *(const bf16x8*)&W_s[n * DM + ((ks * 16 + g * 8) ^ ((n & 7) << 3))];
        acc2[tt] = __builtin_amdgcn_mfma_f32_32x32x16_bf16(af[ks], b, acc2[tt], 0, 0, 0);
      }
#pragma unroll
    for (int tt = 0; tt < 2; ++tt) {
      const int col = n0 + tt * 32 + l31;
      const float bv = bias[col];
      if (mat == 2) {
#pragma unroll
        for (int rq = 0; rq < 4; ++rq) {
          int m = mrowbase + 8 * rq + 4 * g;
          bf16x4 v;
#pragma unroll
          for (int j = 0; j < 4; ++j) v[j] = (__bf16)(acc2[tt][rq * 4 + j] + bv);
          *(bf16x4*)&xvT[(size_t)col * NROWS + m] = v;
        }
      } else {
        __bf16* dst = (mat == 0) ? xqb : xkb;
#pragma unroll
        for (int rq = 0; rq < 4; ++rq)
#pragma unroll
          for (int j = 0; j < 4; ++j) {
            int m = mrowbase + j + 8 * rq + 4 * g;
            dst[(size_t)m * DM + col] = (__bf16)((acc2[tt][rq * 4 + j] + bv) * oscale);
          }
      }
    }
    __syncthreads();  // all waves done reading W_s before next stage
  }
}

// ---- flash staging (JB=32): K tile [32][256] + VT tile [256][32] ----
__device__ __forceinline__ void stage_tiles32(
    const __bf16* __restrict__ xkb, const __bf16* __restrict__ xvT,
    __bf16* Kbuf, __bf16* Vbuf, int j0, int w, int l) {
#pragma unroll
  for (int o = 0; o < 4; ++o) {
    int cbase = o * 256 + w * 64;
    int c = cbase + l;
    int j = c >> 5, kg = (c & 31) * 16;
    load_lds16((const char*)xkb + (size_t)(j0 + j) * 512 + (kg ^ ((j & 15) << 4)),
               (char*)Kbuf + (size_t)cbase * 16);
  }
#pragma unroll
  for (int o = 0; o < 4; ++o) {
    int cbase = o * 256 + w * 64;
    int c = cbase + l;
    int p = c ^ ((c >> 3) & 7);  // involution (bits>=3 unmodified)
    int v = p >> 2, jg = p & 3;
    load_lds16((const char*)xvT + (size_t)v * 16384 + (size_t)j0 * 2 + jg * 16,
               (char*)Vbuf + (size_t)cbase * 16);
  }
}

// ---- fused label-masked softmax-contrastive flash kernel ----
// r16 structure (JB=32, 2 blocks/CU, 4 waves = 2qh x 2vh, acc[4], single
// barrier/iter, depth-1 prefetch, 16-row K swizzle) + SPLIT-C: the S-phase
// accumulator is split into two independent chains (ca: even ks, cb: odd ks)
// to double MFMA ILP (2 chains x 2 waves = 4-way interleave over the
// dependent-MFMA latency). The ca+cb add folds into the softmax loop.
// +16 VGPR (~200 live total, below the 256 cap at 2 waves/SIMD).
__global__ __launch_bounds__(256, 2) void flash_kernel(
    const __bf16* __restrict__ xqb, const __bf16* __restrict__ xkb,
    const __bf16* __restrict__ xvT, const int* __restrict__ lab1,
    const int* __restrict__ lab2, __bf16* __restrict__ accp,
    float* __restrict__ sgp, float* __restrict__ psp) {
  __shared__ __align__(16) char smem[67584];
  __bf16* K_s0 = (__bf16*)smem;                // [2][32*256] = 32 KB
  __bf16* VT_s0 = (__bf16*)(smem + 32768);     // [2][256*32] = 32 KB
  unsigned* lpk = (unsigned*)(smem + 65536);   // 2 KB packed u8 labels (2048 j)

  const int t = threadIdx.x;
  const int w = t >> 6, l = t & 63, g = l >> 5, l31 = l & 31;
  const int qh = w >> 1, vh = w & 1;
  const int f = blockIdx.x;
  const int js = f & 3;   // one chunk per XCD under round-robin
  const int qb = f >> 2;  // 0..127
  const int j0base = js * 2048;

  {  // pack this chunk's labels as bytes (256 thr x 8 labels)
#pragma unroll
    for (int i = 0; i < 2; ++i) {
      int idx = t * 2 + i;
      int4 lv = *(const int4*)&lab2[j0base + idx * 4];
      lpk[idx] = (unsigned)(lv.x & 255) | ((unsigned)(lv.y & 255) << 8) |
                 ((unsigned)(lv.z & 255) << 16) | ((unsigned)(lv.w & 255) << 24);
    }
  }

  const int qrow = qb * 64 + qh * 32 + l31;
  bf16x8 qf[16];
#pragma unroll
  for (int ks = 0; ks < 16; ++ks)
    qf[ks] = *(const bf16x8*)&xqb[(size_t)qrow * DM + ks * 16 + g * 8];
  const unsigned lax = (unsigned)(lab1[qrow] & 255) * 0x01010101u;

  float s_p = 0.f, ps_p = 0.f;
  f32x16 acc[4];
#pragma unroll
  for (int tt = 0; tt < 4; ++tt) acc[tt] = fzero16();

  __syncthreads();  // lpk visible; all prologue vmem drained (vmcnt==0)

  stage_tiles32(xkb, xvT, K_s0, VT_s0, j0base, w, l);  // tile 0 only

  union PaU { unsigned uu[4]; bf16x8 v; };

#pragma unroll 1
  for (int it = 0; it < 64; ++it) {
    // stage(it) is the only outstanding load batch -> vmcnt(0) == landed
    asm volatile("s_waitcnt vmcnt(0)" ::: "memory");
    __builtin_amdgcn_sched_barrier(0);
    __builtin_amdgcn_s_barrier();  // all waves done with iter it-1
    __builtin_amdgcn_sched_barrier(0);

    // prefetch tile it+1 into buf((it+1)&1): last read at iter it-1 -> free
    if (it + 1 < 64)
      stage_tiles32(xkb, xvT, K_s0 + ((it + 1) & 1) * 8192,
                    VT_s0 + ((it + 1) & 1) * 8192, j0base + (it + 1) * 32, w, l);

    const __bf16* Kc = K_s0 + (it & 1) * 8192;
    const __bf16* Vc = VT_s0 + (it & 1) * 8192;

    // ---- S = K@Q^T (32 j): TWO independent accumulator chains ----
    f32x16 ca = fzero16(), cb = fzero16();
    __builtin_amdgcn_s_setprio(1);
#pragma unroll
    for (int ks = 0; ks < 16; ks += 2) {
      bf16x8 kb0 = *(const bf16x8*)&Kc[l31 * DM +
                                       ((ks * 16 + g * 8) ^ ((l31 & 15) << 3))];
      bf16x8 kb1 = *(const bf16x8*)&Kc[l31 * DM +
                                       (((ks + 1) * 16 + g * 8) ^ ((l31 & 15) << 3))];
      ca = __builtin_amdgcn_mfma_f32_32x32x16_bf16(kb0, qf[ks], ca, 0, 0, 0);
      cb = __builtin_amdgcn_mfma_f32_32x32x16_bf16(kb1, qf[ks + 1], cb, 0, 0, 0);
    }
    __builtin_amdgcn_s_setprio(0);

    // ---- softmax + mask (sv = 1.4427*S; exp2); stats for own j-half ----
    unsigned lb[4];
#pragma unroll
    for (int q4 = 0; q4 < 4; ++q4)
      lb[q4] = lpk[it * 8 + q4 * 2 + g] ^ lax;
#pragma unroll
    for (int r = 0; r < 16; ++r) {
      float sv = ca[r] + cb[r];
      float p = EXP2F(sv);
      bool mt = ((lb[r >> 2] >> ((r & 3) * 8)) & 255u) == 0u;
      if ((r >> 3) == vh) {  // compile-time predicate per unrolled r
        s_p += p;
        ps_p += mt ? sv : 0.f;
      }
      ca[r] = mt ? p : 0.f;
    }
    unsigned u[8];
#pragma unroll
    for (int i = 0; i < 8; ++i) u[i] = cvtpk_bf16(ca[2 * i], ca[2 * i + 1]);
    swap32(u[0], u[2]); swap32(u[1], u[3]);
    swap32(u[4], u[6]); swap32(u[5], u[7]);
    PaU p0, p1;
    p0.uu[0] = u[0]; p0.uu[1] = u[1]; p0.uu[2] = u[2]; p0.uu[3] = u[3];
    p1.uu[0] = u[4]; p1.uu[1] = u[5]; p1.uu[2] = u[6]; p1.uu[3] = u[7];

    // ---- PV: acc[32q on regs][128v on lanes] += P @ V (32 j) ----
    __builtin_amdgcn_s_setprio(1);
#pragma unroll
    for (int tt = 0; tt < 4; ++tt) {
      int v = vh * 128 + tt * 32 + l31;
#pragma unroll
      for (int kj = 0; kj < 2; ++kj) {
        int pg = v * 4 + kj * 2 + g;            // logical 16B granule
        int lg = pg ^ ((pg >> 3) & 7);          // swizzled LDS granule
        bf16x8 vb = *(const bf16x8*)&Vc[lg * 8];
        acc[tt] = __builtin_amdgcn_mfma_f32_32x32x16_bf16(
            kj ? p1.v : p0.v, vb, acc[tt], 0, 0, 0);
      }
    }
    __builtin_amdgcn_s_setprio(0);
    // (no second barrier: buffer overwrite is protected by the NEXT iter's
    // top barrier; ds-read results are consumed before that barrier.)
  }

  // ---- epilogue: pair-combine stats (lpk space dead) + accp stores ----
  s_p += __shfl_xor(s_p, 32);
  ps_p += __shfl_xor(ps_p, 32);
  float* sred = (float*)(smem + 65536);  // 4 waves x 32 x 2 f32 = 1 KB
  if (l < 32) {
    sred[(w * 32 + l31) * 2] = s_p;
    sred[(w * 32 + l31) * 2 + 1] = ps_p;
  }
  __syncthreads();
  if (vh == 0 && l < 32) {
    float stot = s_p + sred[(((w ^ 1) * 32) + l31) * 2];
    float ptot = ps_p + sred[(((w ^ 1) * 32) + l31) * 2 + 1];
    sgp[(size_t)js * NROWS + qrow] = stot;
    psp[(size_t)js * NROWS + qrow] = ptot;
  }
  // stage acc (bf16) into padded LDS tile [64][264]
  __bf16* st = (__bf16*)smem;
#pragma unroll
  for (int tt = 0; tt < 4; ++tt)
#pragma unroll
    for (int r = 0; r < 16; ++r) {
      int row = qh * 32 + (r & 3) + 8 * (r >> 2) + 4 * g;
      int col = vh * 128 + tt * 32 + l31;
      st[row * 264 + col] = (__bf16)acc[tt][r];
    }
  __syncthreads();
  // linear copy LDS -> accp: 16B/lane, consecutive lanes -> consecutive 16B
  __bf16* dst = accp + ((size_t)js * NROWS + qb * 64) * DM;
#pragma unroll
  for (int p = 0; p < 8; ++p) {
    int off16 = p * 256 + t;   // 16B-granule index, 0..2047 (32 KB payload)
    int row = off16 >> 5;      // 32 granules (512 B) per row
    int colg = off16 & 31;
    bf16x8 v = *(const bf16x8*)&st[row * 264 + colg * 8];
    *(bf16x8*)&dst[(size_t)row * DM + colg * 8] = v;
  }
}

// ---- combine: sum 4 js partials; out=acc/s; res=x1+out; normalize; loss ----
__global__ __launch_bounds__(1024) void combine_kernel(
    const __bf16* __restrict__ accp, const float* __restrict__ sgp,
    const float* __restrict__ psp, const int* __restrict__ counts,
    const int* __restrict__ lab1, const float* __restrict__ x1,
    __bf16* __restrict__ resn, float* __restrict__ loss_out) {
  __shared__ float lred[16];
  const int t = threadIdx.x;
  const int rr = t >> 6;
  const int r = blockIdx.x * 16 + rr;
  const int l = t & 63;
  float s = 0.f;
#pragma unroll
  for (int js = 0; js < JSPLIT; ++js) s += sgp[(size_t)js * NROWS + r];
  const float inv = 1.f / s;
  float a0 = 0.f, a1 = 0.f, a2 = 0.f, a3 = 0.f;
#pragma unroll
  for (int js = 0; js < JSPLIT; ++js) {
    bf16x4 v = *(const bf16x4*)&accp[((size_t)js * NROWS + r) * DM + l * 4];
    a0 += (float)v[0]; a1 += (float)v[1]; a2 += (float)v[2]; a3 += (float)v[3];
  }
  float4 x = *(const float4*)&x1[(size_t)r * DM + l * 4];
  float o0 = x.x + a0 * inv, o1 = x.y + a1 * inv;
  float o2 = x.z + a2 * inv, o3 = x.w + a3 * inv;
  float sq = o0 * o0 + o1 * o1 + o2 * o2 + o3 * o3;
#pragma unroll
  for (int m = 1; m < 64; m <<= 1) sq += __shfl_xor(sq, m);
  const float nrm = 1.f / fmaxf(sqrtf(sq), 1e-12f);
  bf16x4 o;
  o[0] = (__bf16)(o0 * nrm); o[1] = (__bf16)(o1 * nrm);
  o[2] = (__bf16)(o2 * nrm); o[3] = (__bf16)(o3 * nrm);
  *(bf16x4*)&resn[(size_t)r * DM + l * 4] = o;
  if (l == 0) {
    float ps = 0.f;
#pragma unroll
    for (int js = 0; js < JSPLIT; ++js) ps += psp[(size_t)js * NROWS + r];
    float np = (float)counts[lab1[r] & 15];
    lred[rr] = (ps * LN2F - np * logf(s)) / fmaxf(np, 1.f);
  }
  __syncthreads();
  if (t == 0) {
    float accl = 0.f;
#pragma unroll
    for (int i = 0; i < 16; ++i) accl += lred[i];
    atomicAdd(loss_out, -accl * (1.f / 8192.f));
  }
}

// ---- final GEMM: out[m][n] = relu(resn@Wout + bout), scalar f32 stores ----
__global__ __launch_bounds__(256) void final_gemm(
    const __bf16* __restrict__ A, const __bf16* __restrict__ wmat,
    const float* __restrict__ bias, float* __restrict__ C) {
  __shared__ __bf16 W_s[64 * 256];
  const int t = threadIdx.x;
  const int w = t >> 6, l = t & 63, g = l >> 5, l31 = l & 31;
  const int mb = blockIdx.x, nt = blockIdx.y;
  const int n0 = nt * 64;
#pragma unroll
  for (int o = 0; o < 8; ++o) {
    int cbase = w * 64 + o * 256;
    int chunk = cbase + l;
    int n = chunk >> 5, kb = (chunk & 31) * 16;
    load_lds16((const char*)wmat + (size_t)(n0 + n) * 512 + (kb ^ ((n & 7) << 4)),
               (char*)W_s + (size_t)cbase * 16);
  }
  const int arow = mb * 128 + w * 32 + l31;
  bf16x8 af[16];
#pragma unroll
  for (int ks = 0; ks < 16; ++ks)
    af[ks] = *(const bf16x8*)&A[(size_t)arow * DM + ks * 16 + g * 8];
  __syncthreads();
  f32x16 acc2[2];
  acc2[0] = fzero16(); acc2[1] = fzero16();
#pragma unroll
  for (int ks = 0; ks < 16; ++ks)
#pragma unroll
    for (int tt = 0; tt < 2; ++tt) {
      int n = tt * 32 + l31;
      bf16x8 b = *(const bf16x8*)&W_s[n * DM + ((ks * 16 + g * 8) ^ ((n & 7) << 3))];
      acc2[tt] = __builtin_amdgcn_mfma_f32_32x32x16_bf16(af[ks], b, acc2[tt], 0, 0, 0);
    }
  const int mrowbase = mb * 128 + w * 32;
#pragma unroll
  for (int tt = 0; tt < 2; ++tt) {
    const int col = n0 + tt * 32 + l31;
    const float bv = bias[col];
#pragma unroll
    for (int rq = 0; rq < 4; ++rq)
#pragma unroll
      for (int j = 0; j < 4; ++j) {
        int m = mrowbase + j + 8 * rq + 4 * g;
        C[(size_t)m * DM + col] = fmaxf(acc2[tt][rq * 4 + j] + bv, 0.f);
      }
  }
}

extern "C" void kernel_launch(void* const* d_in, const int* in_sizes, int n_in,
                              void* d_out, int out_size, void* d_ws, size_t ws_size,
                              hipStream_t stream) {
  const float* x1 = (const float*)d_in[0];
  const float* x2 = (const float*)d_in[1];
  const int* lab1 = (const int*)d_in[2];
  const int* lab2 = (const int*)d_in[3];
  const float* Wxq = (const float*)d_in[4];
  const float* bxq = (const float*)d_in[5];
  const float* Wxk = (const float*)d_in[6];
  const float* bxk = (const float*)d_in[7];
  const float* Wxv = (const float*)d_in[8];
  const float* bxv = (const float*)d_in[9];
  const float* Wout = (const float*)d_in[10];
  const float* bout = (const float*)d_in[11];
  float* out = (float*)d_out;

  char* ws = (char*)d_ws;
  __bf16* xqb = (__bf16*)ws;                                // 4 MB
  __bf16* xkb = (__bf16*)(ws + (4 << 20));                  // 4 MB
  __bf16* xvT = (__bf16*)(ws + (8 << 20));                  // 4 MB [256][8192]
  __bf16* wt  = (__bf16*)(ws + (12 << 20));                 // 512 KB
  int* counts = (int*)(ws + (12 << 20) + (512 << 10));      // 64 B
  __bf16* accp = (__bf16*)(ws + (13 << 20));                // 16 MB [4][8192][256]
  float* sgp  = (float*)(ws + (29 << 20));                  // 128 KB [4][8192]
  float* psp  = (float*)(ws + (29 << 20) + (128 << 10));    // 128 KB
  __bf16* resn = xqb;  // alias: xqb dead after flash

  prep_kernel<<<dim3(65), dim3(256), 0, stream>>>(Wxq, Wxk, Wxv, Wout, wt,
                                                  lab2, counts, out);

  proj3_kernel<<<dim3(64, 1, 3), dim3(256), 0, stream>>>(
      x1, x2, wt, bxq, bxk, bxv, xqb, xkb, xvT);

  flash_kernel<<<dim3(512), dim3(256), 0, stream>>>(
      xqb, xkb, xvT, lab1, lab2, accp, sgp, psp);

  combine_kernel<<<dim3(512), dim3(1024), 0, stream>>>(
      accp, sgp, psp, counts, lab1, x1, resn, out);

  final_gemm<<<dim3(64, 4), dim3(256), 0, stream>>>(resn, wt + 196608, bout,
                                                    out + 1);
}

// Round 18
// 164.309 us; speedup vs baseline: 1.0328x; 1.0193x over previous
//
#include <hip/hip_runtime.h>
#include <math.h>

#define DM 256
#define NROWS 8192
#define NCOLS 8192
#define JSPLIT 4
#define LOG2E 1.44269504f
#define LN2F 0.6931471805599453f

typedef __attribute__((ext_vector_type(8)))  __bf16 bf16x8;
typedef __attribute__((ext_vector_type(4)))  __bf16 bf16x4;
typedef __attribute__((ext_vector_type(16))) float  f32x16;

#if __has_builtin(__builtin_amdgcn_exp2f)
#define EXP2F(x) __builtin_amdgcn_exp2f(x)
#else
#define EXP2F(x) exp2f(x)
#endif

__device__ __forceinline__ f32x16 fzero16() {
  f32x16 z;
#pragma unroll
  for (int i = 0; i < 16; ++i) z[i] = 0.f;
  return z;
}

__device__ __forceinline__ void load_lds16(const void* g, void* l) {
  __builtin_amdgcn_global_load_lds(
      (const __attribute__((address_space(1))) unsigned int*)g,
      (__attribute__((address_space(3))) unsigned int*)l, 16, 0, 0);
}

__device__ __forceinline__ bf16x8 cvt8(float4 a, float4 b) {
  bf16x8 v;
  v[0] = (__bf16)a.x; v[1] = (__bf16)a.y; v[2] = (__bf16)a.z; v[3] = (__bf16)a.w;
  v[4] = (__bf16)b.x; v[5] = (__bf16)b.y; v[6] = (__bf16)b.z; v[7] = (__bf16)b.w;
  return v;
}

__device__ __forceinline__ unsigned cvtpk_bf16(float lo, float hi) {
  unsigned r;
  asm("v_cvt_pk_bf16_f32 %0, %1, %2" : "=v"(r) : "v"(lo), "v"(hi));
  return r;
}
__device__ __forceinline__ void swap32(unsigned& a, unsigned& b) {
  asm("v_permlane32_swap_b32 %0, %1" : "+v"(a), "+v"(b));
}

// ---- prep: W transpose+cvt (blocks 0..63) + label hist + loss zero (64) ----
__global__ __launch_bounds__(256) void prep_kernel(
    const float* __restrict__ W0, const float* __restrict__ W1,
    const float* __restrict__ W2, const float* __restrict__ W3,
    __bf16* __restrict__ wt, const int* __restrict__ lab2,
    int* __restrict__ counts, float* __restrict__ loss_out) {
  const int t = threadIdx.x;
  if (blockIdx.x == 64) {
    __shared__ int h[16];
    if (t < 16) h[t] = 0;
    __syncthreads();
#pragma unroll
    for (int i = 0; i < 8; ++i) {
      int4 a = *(const int4*)&lab2[t * 32 + i * 4];
      atomicAdd(&h[a.x & 15], 1); atomicAdd(&h[a.y & 15], 1);
      atomicAdd(&h[a.z & 15], 1); atomicAdd(&h[a.w & 15], 1);
    }
    __syncthreads();
    if (t < 16) counts[t] = h[t];
    if (t == 0) *loss_out = 0.f;
    return;
  }
  __shared__ float Ls[64][65];
  const int mat = blockIdx.x >> 4;
  const int k0 = ((blockIdx.x >> 2) & 3) * 64;
  const int n0 = (blockIdx.x & 3) * 64;
  const float* W = mat == 0 ? W0 : mat == 1 ? W1 : mat == 2 ? W2 : W3;
#pragma unroll
  for (int i = 0; i < 4; ++i) {
    int idx = t + i * 256;
    int row = idx >> 4, c4 = (idx & 15) * 4;
    float4 v = *(const float4*)&W[(size_t)(k0 + row) * DM + n0 + c4];
    Ls[row][c4] = v.x; Ls[row][c4 + 1] = v.y;
    Ls[row][c4 + 2] = v.z; Ls[row][c4 + 3] = v.w;
  }
  __syncthreads();
#pragma unroll
  for (int i = 0; i < 2; ++i) {
    int c = t + i * 256;
    int n = c >> 3, kc = (c & 7) * 8;
    bf16x8 v;
#pragma unroll
    for (int j = 0; j < 8; ++j) v[j] = (__bf16)Ls[kc + j][n];
    *(bf16x8*)&wt[(size_t)mat * 65536 + (size_t)(n0 + n) * DM + k0 + kc] = v;
  }
}

// ---- fused 3-projection MFMA GEMM (grid (64,1,3); internal n-tile loop) ----
__global__ __launch_bounds__(256) void proj3_kernel(
    const float* __restrict__ x1, const float* __restrict__ x2,
    const __bf16* __restrict__ wt, const float* __restrict__ bxq,
    const float* __restrict__ bxk, const float* __restrict__ bxv,
    __bf16* __restrict__ xqb, __bf16* __restrict__ xkb,
    __bf16* __restrict__ xvT) {
  __shared__ __bf16 W_s[64 * 256];
  const int t = threadIdx.x;
  const int w = t >> 6, l = t & 63, g = l >> 5, l31 = l & 31;
  const int mb = blockIdx.x, mat = blockIdx.z;
  const float* A = (mat == 0) ? x1 : x2;
  const __bf16* wmat = wt + (size_t)mat * 65536;
  const float* bias = (mat == 0) ? bxq : (mat == 1) ? bxk : bxv;
  const float oscale = (mat == 0) ? (0.0625f * LOG2E) : 1.0f;
  const int arow = mb * 128 + w * 32 + l31;
  bf16x8 af[16];
#pragma unroll
  for (int ks = 0; ks < 16; ++ks) {
    float4 u0 = *(const float4*)&A[(size_t)arow * DM + ks * 16 + g * 8];
    float4 u1 = *(const float4*)&A[(size_t)arow * DM + ks * 16 + g * 8 + 4];
    af[ks] = cvt8(u0, u1);
  }
  const int mrowbase = mb * 128 + w * 32;
#pragma unroll 1
  for (int nt = 0; nt < 4; ++nt) {
    const int n0 = nt * 64;
#pragma unroll
    for (int o = 0; o < 8; ++o) {
      int cbase = w * 64 + o * 256;
      int chunk = cbase + l;
      int n = chunk >> 5, kb = (chunk & 31) * 16;
      load_lds16((const char*)wmat + (size_t)(n0 + n) * 512 + (kb ^ ((n & 7) << 4)),
                 (char*)W_s + (size_t)cbase * 16);
    }
    __syncthreads();  // staging landed (implicit vmcnt drain)
    f32x16 acc2[2];
    acc2[0] = fzero16(); acc2[1] = fzero16();
#pragma unroll
    for (int ks = 0; ks < 16; ++ks)
#pragma unroll
      for (int tt = 0; tt < 2; ++tt) {
        int n = tt * 32 + l31;
        bf16x8 b = *(const bf16x8*)&W_s[n * DM + ((ks * 16 + g * 8) ^ ((n & 7) << 3))];
        acc2[tt] = __builtin_amdgcn_mfma_f32_32x32x16_bf16(af[ks], b, acc2[tt], 0, 0, 0);
      }
#pragma unroll
    for (int tt = 0; tt < 2; ++tt) {
      const int col = n0 + tt * 32 + l31;
      const float bv = bias[col];
      if (mat == 2) {
#pragma unroll
        for (int rq = 0; rq < 4; ++rq) {
          int m = mrowbase + 8 * rq + 4 * g;
          bf16x4 v;
#pragma unroll
          for (int j = 0; j < 4; ++j) v[j] = (__bf16)(acc2[tt][rq * 4 + j] + bv);
          *(bf16x4*)&xvT[(size_t)col * NROWS + m] = v;
        }
      } else {
        __bf16* dst = (mat == 0) ? xqb : xkb;
#pragma unroll
        for (int rq = 0; rq < 4; ++rq)
#pragma unroll
          for (int j = 0; j < 4; ++j) {
            int m = mrowbase + j + 8 * rq + 4 * g;
            dst[(size_t)m * DM + col] = (__bf16)((acc2[tt][rq * 4 + j] + bv) * oscale);
          }
      }
    }
    __syncthreads();  // all waves done reading W_s before next stage
  }
}

// ---- flash staging (JB=32): K tile [32][256] + VT tile [256][32] ----
__device__ __forceinline__ void stage_tiles32(
    const __bf16* __restrict__ xkb, const __bf16* __restrict__ xvT,
    __bf16* Kbuf, __bf16* Vbuf, int j0, int w, int l) {
#pragma unroll
  for (int o = 0; o < 4; ++o) {
    int cbase = o * 256 + w * 64;
    int c = cbase + l;
    int j = c >> 5, kg = (c & 31) * 16;
    load_lds16((const char*)xkb + (size_t)(j0 + j) * 512 + (kg ^ ((j & 15) << 4)),
               (char*)Kbuf + (size_t)cbase * 16);
  }
#pragma unroll
  for (int o = 0; o < 4; ++o) {
    int cbase = o * 256 + w * 64;
    int c = cbase + l;
    int p = c ^ ((c >> 3) & 7);  // involution (bits>=3 unmodified)
    int v = p >> 2, jg = p & 3;
    load_lds16((const char*)xvT + (size_t)v * 16384 + (size_t)j0 * 2 + jg * 16,
               (char*)Vbuf + (size_t)cbase * 16);
  }
}

// ---- fused label-masked softmax-contrastive flash kernel (best: r16) ----
// JB=32, 2 blocks/CU, 4 waves = 2qh x 2vh, acc[4], single barrier/iter,
// depth-1 prefetch, 16-row K swizzle, single S accumulator.
__global__ __launch_bounds__(256, 2) void flash_kernel(
    const __bf16* __restrict__ xqb, const __bf16* __restrict__ xkb,
    const __bf16* __restrict__ xvT, const int* __restrict__ lab1,
    const int* __restrict__ lab2, __bf16* __restrict__ accp,
    float* __restrict__ sgp, float* __restrict__ psp) {
  __shared__ __align__(16) char smem[67584];
  __bf16* K_s0 = (__bf16*)smem;                // [2][32*256] = 32 KB
  __bf16* VT_s0 = (__bf16*)(smem + 32768);     // [2][256*32] = 32 KB
  unsigned* lpk = (unsigned*)(smem + 65536);   // 2 KB packed u8 labels (2048 j)

  const int t = threadIdx.x;
  const int w = t >> 6, l = t & 63, g = l >> 5, l31 = l & 31;
  const int qh = w >> 1, vh = w & 1;
  const int f = blockIdx.x;
  const int js = f & 3;   // one chunk per XCD under round-robin
  const int qb = f >> 2;  // 0..127
  const int j0base = js * 2048;

  {  // pack this chunk's labels as bytes (256 thr x 8 labels)
#pragma unroll
    for (int i = 0; i < 2; ++i) {
      int idx = t * 2 + i;
      int4 lv = *(const int4*)&lab2[j0base + idx * 4];
      lpk[idx] = (unsigned)(lv.x & 255) | ((unsigned)(lv.y & 255) << 8) |
                 ((unsigned)(lv.z & 255) << 16) | ((unsigned)(lv.w & 255) << 24);
    }
  }

  const int qrow = qb * 64 + qh * 32 + l31;
  bf16x8 qf[16];
#pragma unroll
  for (int ks = 0; ks < 16; ++ks)
    qf[ks] = *(const bf16x8*)&xqb[(size_t)qrow * DM + ks * 16 + g * 8];
  const unsigned lax = (unsigned)(lab1[qrow] & 255) * 0x01010101u;

  float s_p = 0.f, ps_p = 0.f;
  f32x16 acc[4];
#pragma unroll
  for (int tt = 0; tt < 4; ++tt) acc[tt] = fzero16();

  __syncthreads();  // lpk visible; all prologue vmem drained (vmcnt==0)

  stage_tiles32(xkb, xvT, K_s0, VT_s0, j0base, w, l);  // tile 0 only

  union PaU { unsigned uu[4]; bf16x8 v; };

#pragma unroll 1
  for (int it = 0; it < 64; ++it) {
    // stage(it) is the only outstanding load batch -> vmcnt(0) == landed
    asm volatile("s_waitcnt vmcnt(0)" ::: "memory");
    __builtin_amdgcn_sched_barrier(0);
    __builtin_amdgcn_s_barrier();  // all waves done with iter it-1
    __builtin_amdgcn_sched_barrier(0);

    // prefetch tile it+1 into buf((it+1)&1): last read at iter it-1 -> free
    if (it + 1 < 64)
      stage_tiles32(xkb, xvT, K_s0 + ((it + 1) & 1) * 8192,
                    VT_s0 + ((it + 1) & 1) * 8192, j0base + (it + 1) * 32, w, l);

    const __bf16* Kc = K_s0 + (it & 1) * 8192;
    const __bf16* Vc = VT_s0 + (it & 1) * 8192;

    // ---- S = K@Q^T (32 j): c[j on regs][q on lanes] ----
    f32x16 c = fzero16();
    __builtin_amdgcn_s_setprio(1);
#pragma unroll
    for (int ks = 0; ks < 16; ++ks) {
      bf16x8 kb = *(const bf16x8*)&Kc[l31 * DM +
                                      ((ks * 16 + g * 8) ^ ((l31 & 15) << 3))];
      c = __builtin_amdgcn_mfma_f32_32x32x16_bf16(kb, qf[ks], c, 0, 0, 0);
    }
    __builtin_amdgcn_s_setprio(0);

    // ---- softmax + mask (c = 1.4427*S; exp2); stats for own j-half ----
    unsigned lb[4];
#pragma unroll
    for (int q4 = 0; q4 < 4; ++q4)
      lb[q4] = lpk[it * 8 + q4 * 2 + g] ^ lax;
#pragma unroll
    for (int r = 0; r < 16; ++r) {
      float sv = c[r];
      float p = EXP2F(sv);
      bool mt = ((lb[r >> 2] >> ((r & 3) * 8)) & 255u) == 0u;
      if ((r >> 3) == vh) {  // compile-time predicate per unrolled r
        s_p += p;
        ps_p += mt ? sv : 0.f;
      }
      c[r] = mt ? p : 0.f;
    }
    unsigned u[8];
#pragma unroll
    for (int i = 0; i < 8; ++i) u[i] = cvtpk_bf16(c[2 * i], c[2 * i + 1]);
    swap32(u[0], u[2]); swap32(u[1], u[3]);
    swap32(u[4], u[6]); swap32(u[5], u[7]);
    PaU p0, p1;
    p0.uu[0] = u[0]; p0.uu[1] = u[1]; p0.uu[2] = u[2]; p0.uu[3] = u[3];
    p1.uu[0] = u[4]; p1.uu[1] = u[5]; p1.uu[2] = u[6]; p1.uu[3] = u[7];

    // ---- PV: acc[32q on regs][128v on lanes] += P @ V (32 j) ----
    __builtin_amdgcn_s_setprio(1);
#pragma unroll
    for (int tt = 0; tt < 4; ++tt) {
      int v = vh * 128 + tt * 32 + l31;
#pragma unroll
      for (int kj = 0; kj < 2; ++kj) {
        int pg = v * 4 + kj * 2 + g;            // logical 16B granule
        int lg = pg ^ ((pg >> 3) & 7);          // swizzled LDS granule
        bf16x8 vb = *(const bf16x8*)&Vc[lg * 8];
        acc[tt] = __builtin_amdgcn_mfma_f32_32x32x16_bf16(
            kj ? p1.v : p0.v, vb, acc[tt], 0, 0, 0);
      }
    }
    __builtin_amdgcn_s_setprio(0);
    // (no second barrier: buffer overwrite is protected by the NEXT iter's
    // top barrier; ds-read results are consumed before that barrier.)
  }

  // ---- epilogue: pair-combine stats (lpk space dead) + accp stores ----
  s_p += __shfl_xor(s_p, 32);
  ps_p += __shfl_xor(ps_p, 32);
  float* sred = (float*)(smem + 65536);  // 4 waves x 32 x 2 f32 = 1 KB
  if (l < 32) {
    sred[(w * 32 + l31) * 2] = s_p;
    sred[(w * 32 + l31) * 2 + 1] = ps_p;
  }
  __syncthreads();
  if (vh == 0 && l < 32) {
    float stot = s_p + sred[(((w ^ 1) * 32) + l31) * 2];
    float ptot = ps_p + sred[(((w ^ 1) * 32) + l31) * 2 + 1];
    sgp[(size_t)js * NROWS + qrow] = stot;
    psp[(size_t)js * NROWS + qrow] = ptot;
  }
  // stage acc (bf16) into padded LDS tile [64][264]
  __bf16* st = (__bf16*)smem;
#pragma unroll
  for (int tt = 0; tt < 4; ++tt)
#pragma unroll
    for (int r = 0; r < 16; ++r) {
      int row = qh * 32 + (r & 3) + 8 * (r >> 2) + 4 * g;
      int col = vh * 128 + tt * 32 + l31;
      st[row * 264 + col] = (__bf16)acc[tt][r];
    }
  __syncthreads();
  // linear copy LDS -> accp: 16B/lane, consecutive lanes -> consecutive 16B
  __bf16* dst = accp + ((size_t)js * NROWS + qb * 64) * DM;
#pragma unroll
  for (int p = 0; p < 8; ++p) {
    int off16 = p * 256 + t;   // 16B-granule index, 0..2047 (32 KB payload)
    int row = off16 >> 5;      // 32 granules (512 B) per row
    int colg = off16 & 31;
    bf16x8 v = *(const bf16x8*)&st[row * 264 + colg * 8];
    *(bf16x8*)&dst[(size_t)row * DM + colg * 8] = v;
  }
}

// ---- combine: sum 4 js partials; out=acc/s; res=x1+out; normalize; loss ----
__global__ __launch_bounds__(1024) void combine_kernel(
    const __bf16* __restrict__ accp, const float* __restrict__ sgp,
    const float* __restrict__ psp, const int* __restrict__ counts,
    const int* __restrict__ lab1, const float* __restrict__ x1,
    __bf16* __restrict__ resn, float* __restrict__ loss_out) {
  __shared__ float lred[16];
  const int t = threadIdx.x;
  const int rr = t >> 6;
  const int r = blockIdx.x * 16 + rr;
  const int l = t & 63;
  float s = 0.f;
#pragma unroll
  for (int js = 0; js < JSPLIT; ++js) s += sgp[(size_t)js * NROWS + r];
  const float inv = 1.f / s;
  float a0 = 0.f, a1 = 0.f, a2 = 0.f, a3 = 0.f;
#pragma unroll
  for (int js = 0; js < JSPLIT; ++js) {
    bf16x4 v = *(const bf16x4*)&accp[((size_t)js * NROWS + r) * DM + l * 4];
    a0 += (float)v[0]; a1 += (float)v[1]; a2 += (float)v[2]; a3 += (float)v[3];
  }
  float4 x = *(const float4*)&x1[(size_t)r * DM + l * 4];
  float o0 = x.x + a0 * inv, o1 = x.y + a1 * inv;
  float o2 = x.z + a2 * inv, o3 = x.w + a3 * inv;
  float sq = o0 * o0 + o1 * o1 + o2 * o2 + o3 * o3;
#pragma unroll
  for (int m = 1; m < 64; m <<= 1) sq += __shfl_xor(sq, m);
  const float nrm = 1.f / fmaxf(sqrtf(sq), 1e-12f);
  bf16x4 o;
  o[0] = (__bf16)(o0 * nrm); o[1] = (__bf16)(o1 * nrm);
  o[2] = (__bf16)(o2 * nrm); o[3] = (__bf16)(o3 * nrm);
  *(bf16x4*)&resn[(size_t)r * DM + l * 4] = o;
  if (l == 0) {
    float ps = 0.f;
#pragma unroll
    for (int js = 0; js < JSPLIT; ++js) ps += psp[(size_t)js * NROWS + r];
    float np = (float)counts[lab1[r] & 15];
    lred[rr] = (ps * LN2F - np * logf(s)) / fmaxf(np, 1.f);
  }
  __syncthreads();
  if (t == 0) {
    float accl = 0.f;
#pragma unroll
    for (int i = 0; i < 16; ++i) accl += lred[i];
    atomicAdd(loss_out, -accl * (1.f / 8192.f));
  }
}

// ---- final GEMM: out[m][n] = relu(resn@Wout + bout), scalar f32 stores ----
__global__ __launch_bounds__(256) void final_gemm(
    const __bf16* __restrict__ A, const __bf16* __restrict__ wmat,
    const float* __restrict__ bias, float* __restrict__ C) {
  __shared__ __bf16 W_s[64 * 256];
  const int t = threadIdx.x;
  const int w = t >> 6, l = t & 63, g = l >> 5, l31 = l & 31;
  const int mb = blockIdx.x, nt = blockIdx.y;
  const int n0 = nt * 64;
#pragma unroll
  for (int o = 0; o < 8; ++o) {
    int cbase = w * 64 + o * 256;
    int chunk = cbase + l;
    int n = chunk >> 5, kb = (chunk & 31) * 16;
    load_lds16((const char*)wmat + (size_t)(n0 + n) * 512 + (kb ^ ((n & 7) << 4)),
               (char*)W_s + (size_t)cbase * 16);
  }
  const int arow = mb * 128 + w * 32 + l31;
  bf16x8 af[16];
#pragma unroll
  for (int ks = 0; ks < 16; ++ks)
    af[ks] = *(const bf16x8*)&A[(size_t)arow * DM + ks * 16 + g * 8];
  __syncthreads();
  f32x16 acc2[2];
  acc2[0] = fzero16(); acc2[1] = fzero16();
#pragma unroll
  for (int ks = 0; ks < 16; ++ks)
#pragma unroll
    for (int tt = 0; tt < 2; ++tt) {
      int n = tt * 32 + l31;
      bf16x8 b = *(const bf16x8*)&W_s[n * DM + ((ks * 16 + g * 8) ^ ((n & 7) << 3))];
      acc2[tt] = __builtin_amdgcn_mfma_f32_32x32x16_bf16(af[ks], b, acc2[tt], 0, 0, 0);
    }
  const int mrowbase = mb * 128 + w * 32;
#pragma unroll
  for (int tt = 0; tt < 2; ++tt) {
    const int col = n0 + tt * 32 + l31;
    const float bv = bias[col];
#pragma unroll
    for (int rq = 0; rq < 4; ++rq)
#pragma unroll
      for (int j = 0; j < 4; ++j) {
        int m = mrowbase + j + 8 * rq + 4 * g;
        C[(size_t)m * DM + col] = fmaxf(acc2[tt][rq * 4 + j] + bv, 0.f);
      }
  }
}

extern "C" void kernel_launch(void* const* d_in, const int* in_sizes, int n_in,
                              void* d_out, int out_size, void* d_ws, size_t ws_size,
                              hipStream_t stream) {
  const float* x1 = (const float*)d_in[0];
  const float* x2 = (const float*)d_in[1];
  const int* lab1 = (const int*)d_in[2];
  const int* lab2 = (const int*)d_in[3];
  const float* Wxq = (const float*)d_in[4];
  const float* bxq = (const float*)d_in[5];
  const float* Wxk = (const float*)d_in[6];
  const float* bxk = (const float*)d_in[7];
  const float* Wxv = (const float*)d_in[8];
  const float* bxv = (const float*)d_in[9];
  const float* Wout = (const float*)d_in[10];
  const float* bout = (const float*)d_in[11];
  float* out = (float*)d_out;

  char* ws = (char*)d_ws;
  __bf16* xqb = (__bf16*)ws;                                // 4 MB
  __bf16* xkb = (__bf16*)(ws + (4 << 20));                  // 4 MB
  __bf16* xvT = (__bf16*)(ws + (8 << 20));                  // 4 MB [256][8192]
  __bf16* wt  = (__bf16*)(ws + (12 << 20));                 // 512 KB
  int* counts = (int*)(ws + (12 << 20) + (512 << 10));      // 64 B
  __bf16* accp = (__bf16*)(ws + (13 << 20));                // 16 MB [4][8192][256]
  float* sgp  = (float*)(ws + (29 << 20));                  // 128 KB [4][8192]
  float* psp  = (float*)(ws + (29 << 20) + (128 << 10));    // 128 KB
  __bf16* resn = xqb;  // alias: xqb dead after flash

  prep_kernel<<<dim3(65), dim3(256), 0, stream>>>(Wxq, Wxk, Wxv, Wout, wt,
                                                  lab2, counts, out);

  proj3_kernel<<<dim3(64, 1, 3), dim3(256), 0, stream>>>(
      x1, x2, wt, bxq, bxk, bxv, xqb, xkb, xvT);

  flash_kernel<<<dim3(512), dim3(256), 0, stream>>>(
      xqb, xkb, xvT, lab1, lab2, accp, sgp, psp);

  combine_kernel<<<dim3(512), dim3(1024), 0, stream>>>(
      accp, sgp, psp, counts, lab1, x1, resn, out);

  final_gemm<<<dim3(64, 4), dim3(256), 0, stream>>>(resn, wt + 196608, bout,
                                                    out + 1);
}